// Round 5
// baseline (3461.198 us; speedup 1.0000x reference)
//
#include <hip/hip_runtime.h>
#include <math.h>

#define NBATCH 4096
#define NH2 21
#define NK 77
#define NC 35
#define NIJ 441
#define Y_SIZE 33957
#define M_SIZE 5929
#define VOLOFF Y_SIZE          // vol[n] at out[VOLOFF + n] (temp, inside M region)
#define VSUM (Y_SIZE + 4096)   // volsum at out[VSUM] (temp, inside M region)
#define KT 11                  // k-tile: 7 tiles cover 77
#define CHUNK 16               // n per block
#define NCHUNK (NBATCH / CHUNK)
#define NPAIR 231              // upper-triangular (i<=j) pairs of 21

#define SZ_OMEGA  (NBATCH * NH2 * NH2)   // 1,806,336
#define SZ_PHI    (NBATCH * NK * NC)     // 11,038,720
#define SZ_METRIC (NBATCH * 7 * 7)       // 200,704

// ---------------- compile-time wedge structure constants ----------------
// C[a,b,c] nonzero iff pair_a, pair_b, triple_c partition {0..6}; value = perm
// sign. Exactly 6 (a,b) terms per c. MUST be a constexpr LOCAL in each kernel
// (round-3 finding: __device__ constexpr global risked zero-init).
// Symmetry C[a,b,c]=C[b,a,c] (pair swap = 4 transpositions = even) => D[ij]=D[ji]
// => S symmetric in (i,j): contract computes only i<=j pairs.
struct WTab {
  int a[NC][6];
  int b[NC][6];
  int sg[NC][6];
};

constexpr WTab make_wtab() {
  WTab W{};
  int p0[21] = {}, p1[21] = {};
  int idx = 0;
  for (int x = 0; x < 7; ++x)
    for (int y = x + 1; y < 7; ++y) { p0[idx] = x; p1[idx] = y; ++idx; }
  int t0[35] = {}, t1[35] = {}, t2[35] = {};
  idx = 0;
  for (int x = 0; x < 7; ++x)
    for (int y = x + 1; y < 7; ++y)
      for (int z = y + 1; z < 7; ++z) { t0[idx] = x; t1[idx] = y; t2[idx] = z; ++idx; }
  int cnt[35] = {};
  for (int a = 0; a < 21; ++a)
    for (int b = 0; b < 21; ++b) {
      int pa0 = p0[a], pa1 = p1[a], pb0 = p0[b], pb1 = p1[b];
      if (pa0 == pb0 || pa0 == pb1 || pa1 == pb0 || pa1 == pb1) continue;
      bool used[7] = {};
      used[pa0] = true; used[pa1] = true; used[pb0] = true; used[pb1] = true;
      int tr[3] = {}; int k = 0;
      for (int x = 0; x < 7; ++x) if (!used[x]) tr[k++] = x;
      int c = -1;
      for (int cc = 0; cc < 35; ++cc)
        if (t0[cc] == tr[0] && t1[cc] == tr[1] && t2[cc] == tr[2]) { c = cc; break; }
      int perm[7] = {pa0, pa1, pb0, pb1, tr[0], tr[1], tr[2]};
      int inv = 0;
      for (int i = 0; i < 7; ++i)
        for (int j = i + 1; j < 7; ++j)
          if (perm[i] > perm[j]) ++inv;
      W.a[c][cnt[c]] = a; W.b[c][cnt[c]] = b; W.sg[c][cnt[c]] = (inv & 1) ? -1 : 1;
      ++cnt[c];
    }
  return W;
}

__device__ __forceinline__ int trioff(int i) { return 21 * i - (i * (i - 1)) / 2; }

// ---------------- kernel A: vol[n] = sqrt(|det(metric_n)|), + sum ----------------
__global__ __launch_bounds__(256) void vol_kernel(const float* __restrict__ metric,
                                                  float* __restrict__ out) {
  const int n = blockIdx.x * 256 + threadIdx.x;
  double a[7][7];
#pragma unroll
  for (int r = 0; r < 7; ++r)
#pragma unroll
    for (int c = 0; c < 7; ++c) a[r][c] = (double)metric[n * 49 + r * 7 + c];

  double det = 1.0;
#pragma unroll
  for (int k = 0; k < 7; ++k) {
#pragma unroll
    for (int r = k + 1; r < 7; ++r) {   // bubble max |pivot| into row k
      bool sw = fabs(a[r][k]) > fabs(a[k][k]);
#pragma unroll
      for (int c = k; c < 7; ++c) {
        double u = a[k][c], v = a[r][c];
        a[k][c] = sw ? v : u;
        a[r][c] = sw ? u : v;
      }
    }
    det *= a[k][k];
    double inv = (a[k][k] != 0.0) ? 1.0 / a[k][k] : 0.0;
#pragma unroll
    for (int r = k + 1; r < 7; ++r) {
      double f = a[r][k] * inv;
#pragma unroll
      for (int c = k + 1; c < 7; ++c) a[r][c] -= f * a[k][c];
    }
  }
  float vol = (float)sqrt(fabs(det));
  out[VOLOFF + n] = vol;

  float s = vol;
#pragma unroll
  for (int off = 32; off > 0; off >>= 1) s += __shfl_down(s, off, 64);
  __shared__ float partial[4];
  const int lane = threadIdx.x & 63, wv = threadIdx.x >> 6;
  if (lane == 0) partial[wv] = s;
  __syncthreads();
  if (threadIdx.x == 0)
    atomicAdd(out + VSUM, partial[0] + partial[1] + partial[2] + partial[3]);
}

// ---------------- kernel B: symmetric tiled contract ----------------
// grid (7 k-tiles, 256 n-chunks) x 256 threads. Thread t<231 owns the t-th
// upper-triangular pair (i<=j). Per n: stage omega + vol*Phi k-tile in LDS;
// D[c] once per pair (210 FMAs); acc[kk] += dot(D, pw_row). Flush atomically
// to BOTH (i,j) and (j,i) so downstream kernels see the full symmetric Sraw.
__global__ __launch_bounds__(256, 4) void contract_kernel(const float* __restrict__ omega,
                                                          const float* __restrict__ Phi,
                                                          float* __restrict__ out) {
  constexpr WTab W = make_wtab();
  __shared__ __align__(16) float lds_om[NH2 * 24];  // rows padded to 24 floats
  __shared__ __align__(16) float lds_pw[KT * 36];   // rows padded to 36 floats

  const int t = threadIdx.x;
  const int k0 = blockIdx.x * KT;
  const int n0 = blockIdx.y * CHUNK;
  const bool act = (t < NPAIR);

  // triangular decode: pair t -> (pi <= pj)
  int pi = 0, pj = 0;
  {
    const int p = act ? t : 0;
    int i = (int)((43.0f - sqrtf((float)(1849 - 8 * p))) * 0.5f);
    i = (i < 0) ? 0 : ((i > 20) ? 20 : i);
    while (i < 20 && trioff(i + 1) <= p) ++i;   // integer fixup (fp-edge safety)
    while (i > 0 && trioff(i) > p) --i;
    pi = i;
    pj = p - trioff(i) + i;
  }

  if (t < KT) lds_pw[t * 36 + 35] = 0.0f;  // zero pad col, never overwritten

  float acc[KT];
#pragma unroll
  for (int kk = 0; kk < KT; ++kk) acc[kk] = 0.0f;

  for (int n = n0; n < n0 + CHUNK; ++n) {
    const float vn = out[VOLOFF + n];
    const float* om = omega + n * 441;
    const float* ph = Phi + n * 2695 + k0 * 35;

    __syncthreads();  // previous iteration's consumers done
    {
      int f = t;
      lds_om[(f / 21) * 24 + (f % 21)] = om[f];
      f = t + 256;
      if (f < 441) lds_om[(f / 21) * 24 + (f % 21)] = om[f];
      lds_pw[(t / 35) * 36 + (t % 35)] = vn * ph[t];
      f = t + 256;
      if (f < 385) lds_pw[(f / 35) * 36 + (f % 35)] = vn * ph[f];
    }
    __syncthreads();

    if (act) {
      float wi[21], wj[21];
      const float* oi = lds_om + pi * 24;
      const float* oj = lds_om + pj * 24;
#pragma unroll
      for (int a = 0; a < 20; a += 4) {
        float4 v = *(const float4*)(oi + a);
        wi[a] = v.x; wi[a + 1] = v.y; wi[a + 2] = v.z; wi[a + 3] = v.w;
        float4 u = *(const float4*)(oj + a);
        wj[a] = u.x; wj[a + 1] = u.y; wj[a + 2] = u.z; wj[a + 3] = u.w;
      }
      wi[20] = oi[20]; wj[20] = oj[20];

      float d[36];
#pragma unroll
      for (int c = 0; c < 35; ++c) {
        float dd = 0.0f;
#pragma unroll
        for (int u = 0; u < 6; ++u)
          dd = fmaf((W.sg[c][u] > 0) ? wi[W.a[c][u]] : -wi[W.a[c][u]], wj[W.b[c][u]], dd);
        d[c] = dd;
      }
      d[35] = 0.0f;

#pragma unroll
      for (int kk = 0; kk < KT; ++kk) {
        const float* pw = lds_pw + kk * 36;  // wave-uniform -> LDS broadcast
        float s0 = 0.f, s1 = 0.f, s2 = 0.f, s3 = 0.f;
#pragma unroll
        for (int c = 0; c < 36; c += 4) {
          float4 p = *(const float4*)(pw + c);
          s0 = fmaf(d[c + 0], p.x, s0);
          s1 = fmaf(d[c + 1], p.y, s1);
          s2 = fmaf(d[c + 2], p.z, s2);
          s3 = fmaf(d[c + 3], p.w, s3);
        }
        acc[kk] += (s0 + s1) + (s2 + s3);
      }
    }
  }

  if (act) {
    const int base1 = (pi * 21 + pj) * 77 + k0;
    const int base2 = (pj * 21 + pi) * 77 + k0;
#pragma unroll
    for (int kk = 0; kk < KT; ++kk) atomicAdd(&out[base1 + kk], acc[kk]);
    if (pi != pj) {
#pragma unroll
      for (int kk = 0; kk < KT; ++kk) atomicAdd(&out[base2 + kk], acc[kk]);
    }
  }
}

// ---------------- kernel C1: Y = sign * Sraw / volsum, in place ----------------
__global__ __launch_bounds__(256) void finalize_y(float* __restrict__ out) {
  const int e = blockIdx.x * 256 + threadIdx.x;
  if (e >= Y_SIZE) return;
  const float inv = 1.0f / out[VSUM];
  const int ij = e / NK;
  const int i = ij / NH2, j = ij % NH2;
  const float v = out[e] * inv;
  out[e] = (j >= i) ? v : -v;
}

// ---------------- kernel C2: M[k,l] = sum_ij Y_ij,k Y_ij,l (signs cancel) --------
__global__ __launch_bounds__(256) void gram_kernel(const float* __restrict__ Y,
                                                   float* __restrict__ Mout) {
  const int e = blockIdx.x * 256 + threadIdx.x;
  if (e >= M_SIZE) return;
  const int k = e / NK, l = e % NK;
  float acc = 0.0f;
  for (int ij = 0; ij < NIJ; ++ij)
    acc = fmaf(Y[ij * NK + k], Y[ij * NK + l], acc);
  Mout[e] = acc;
}

// ---------------- kernel D: eigvalsh(M), single-wave fp32 ----------------
// One 64-lane wave: barriers are intra-wave (cheap), reductions are shuffles,
// A[77][79] fp32 (odd row stride 79 -> row-major matvec reads conflict-free).
__global__ __launch_bounds__(64) void eig_kernel(const float* __restrict__ Min,
                                                 float* __restrict__ eout) {
  __shared__ float A[77][79];
  __shared__ float vsh[77], wsh[77], esh[77], dsh[77], e2[76];
  __shared__ float glo_s, ghi_s;
  const int t = threadIdx.x;

  for (int f = t; f < M_SIZE; f += 64) A[f / 77][f % 77] = Min[f];
  __syncthreads();

  // Householder tridiagonalization (fp32, rank-2 update)
  for (int k = 0; k < 75; ++k) {
    const int lo = k + 1;

    float part = 0.0f;
    for (int i = lo + t; i <= 76; i += 64) part += A[i][k] * A[i][k];
#pragma unroll
    for (int off = 32; off > 0; off >>= 1) part += __shfl_down(part, off, 64);
    const float sigma2 = __shfl(part, 0, 64);
    const float x1 = A[lo][k];

    if (sigma2 < 1e-30f) {
      if (t == 0) esh[k] = 0.0f;
      __syncthreads();
      continue;
    }
    const float sigma = sqrtf(sigma2);
    const float alpha = (x1 >= 0.0f) ? -sigma : sigma;
    const float beta = 1.0f / (sigma2 - alpha * x1);  // = 2 / (v^T v)

    for (int i = lo + t; i <= 76; i += 64) vsh[i] = (i == lo) ? (x1 - alpha) : A[i][k];
    if (t == 0) esh[k] = alpha;
    __syncthreads();

    // p = beta * A v  (store into wsh), K = p.v
    float part2 = 0.0f;
    for (int i = lo + t; i <= 76; i += 64) {
      float s = 0.0f;
      for (int j = lo; j <= 76; ++j) s += A[i][j] * vsh[j];
      const float p = beta * s;
      wsh[i] = p;
      part2 += p * vsh[i];
    }
#pragma unroll
    for (int off = 32; off > 0; off >>= 1) part2 += __shfl_down(part2, off, 64);
    const float K = __shfl(part2, 0, 64);
    __syncthreads();

    const float hb = 0.5f * beta * K;
    for (int i = lo + t; i <= 76; i += 64) wsh[i] = wsh[i] - hb * vsh[i];
    __syncthreads();

    // A -= v w^T + w v^T  (row-parallel, no integer div)
    for (int ii = lo + t; ii <= 76; ii += 64) {
      const float vi = vsh[ii], wi = wsh[ii];
      for (int jj = lo; jj <= 76; ++jj)
        A[ii][jj] -= vi * wsh[jj] + wi * vsh[jj];
    }
    __syncthreads();
  }

  for (int f = t; f < 77; f += 64) dsh[f] = A[f][f];
  if (t == 0) esh[75] = A[76][75];
  __syncthreads();
  for (int f = t; f < 76; f += 64) e2[f] = esh[f] * esh[f];

  if (t == 0) {  // Gershgorin bounds
    float lo_ = 1e30f, hi_ = -1e30f;
    for (int i = 0; i < 77; ++i) {
      float r = ((i > 0) ? fabsf(esh[i - 1]) : 0.0f) + ((i < 76) ? fabsf(esh[i]) : 0.0f);
      lo_ = fminf(lo_, dsh[i] - r);
      hi_ = fmaxf(hi_, dsh[i] + r);
    }
    const float span = hi_ - lo_;
    glo_s = lo_ - 0.001f * span - 1e-6f;
    ghi_s = hi_ + 0.001f * span + 1e-6f;
  }
  __syncthreads();

  // bisection via Sturm count; lane handles eigenvalues idx and idx+64
  for (int idx = t; idx < 77; idx += 64) {
    float lo = glo_s, hi = ghi_s;
    for (int it = 0; it < 48; ++it) {
      const float mid = 0.5f * (lo + hi);
      float q = dsh[0] - mid;
      int cnt = (q < 0.0f);
      for (int i = 1; i < 77; ++i) {
        if (fabsf(q) < 1e-30f) q = -1e-30f;
        q = dsh[i] - mid - e2[i - 1] / q;
        cnt += (q < 0.0f);
      }
      if (cnt > idx) hi = mid; else lo = mid;
    }
    eout[76 - idx] = 0.5f * (lo + hi);  // descending
  }
}

// ---------------- launch ----------------
extern "C" void kernel_launch(void* const* d_in, const int* in_sizes, int n_in,
                              void* d_out, int out_size, void* d_ws, size_t ws_size,
                              hipStream_t stream) {
  // Inputs selected BY ELEMENT COUNT (all distinct), fallback to dict order.
  const float* omega  = (const float*)d_in[0];
  const float* Phi    = (const float*)d_in[1];
  const float* metric = (const float*)d_in[2];
  for (int q = 0; q < n_in && q < 3; ++q) {
    if (in_sizes[q] == SZ_OMEGA)       omega  = (const float*)d_in[q];
    else if (in_sizes[q] == SZ_PHI)    Phi    = (const float*)d_in[q];
    else if (in_sizes[q] == SZ_METRIC) metric = (const float*)d_in[q];
  }

  float* out = (float*)d_out;

  // All scratch lives inside d_out (d_ws unused):
  //   out[0 .. Y_SIZE)            : Sraw accumulator -> finalized Y
  //   out[VOLOFF .. VOLOFF+4096)  : vol[n] (temp, overwritten by gram's M)
  //   out[VSUM]                   : volsum (temp, overwritten by gram's M)
  hipMemsetAsync(d_out, 0, (size_t)out_size * sizeof(float), stream);

  hipLaunchKernelGGL(vol_kernel, dim3(NBATCH / 256), dim3(256), 0, stream, metric, out);
  hipLaunchKernelGGL(contract_kernel, dim3(7, NCHUNK), dim3(256), 0, stream,
                     omega, Phi, out);
  hipLaunchKernelGGL(finalize_y, dim3((Y_SIZE + 255) / 256), dim3(256), 0, stream, out);
  hipLaunchKernelGGL(gram_kernel, dim3((M_SIZE + 255) / 256), dim3(256), 0, stream,
                     out, out + Y_SIZE);
  hipLaunchKernelGGL(eig_kernel, dim3(1), dim3(64), 0, stream,
                     out + Y_SIZE, out + Y_SIZE + M_SIZE);
}

// Round 6
// 1409.616 us; speedup vs baseline: 2.4554x; 2.4554x over previous
//
#include <hip/hip_runtime.h>
#include <math.h>

#define NBATCH 4096
#define NH2 21
#define NK 77
#define NC 35
#define NIJ 441
#define Y_SIZE 33957
#define M_SIZE 5929
#define VOLOFF Y_SIZE          // vol[n] at out[VOLOFF + n] (temp, inside M region)
#define VSUM (Y_SIZE + 4096)   // volsum at out[VSUM] (temp, inside M region)
#define KT 11                  // k-tile: 7 tiles cover 77
#define CHUNK 16               // n per block
#define NCHUNK (NBATCH / CHUNK)
#define NPAIR 231              // upper-triangular (i<=j) pairs of 21

#define SZ_OMEGA  (NBATCH * NH2 * NH2)   // 1,806,336
#define SZ_PHI    (NBATCH * NK * NC)     // 11,038,720
#define SZ_METRIC (NBATCH * 7 * 7)       // 200,704

// ---------------- compile-time wedge structure constants ----------------
// C[a,b,c] nonzero iff pair_a, pair_b, triple_c partition {0..6}; value = perm
// sign. Exactly 6 (a,b) terms per c. MUST be a constexpr LOCAL in each kernel
// (round-3 finding: __device__ constexpr global risked zero-init).
// C[a,b,c]=C[b,a,c] => S symmetric in (i,j): contract computes only i<=j.
// ROUND-5 LESSON: do NOT cap VGPRs with launch_bounds below the ~90-float live
// set (wi/wj 42 + d 36 + acc 11) — (256,4) forced 64 VGPRs -> spill -> 8.5 GB
// scratch traffic -> 5x regression.
struct WTab {
  int a[NC][6];
  int b[NC][6];
  int sg[NC][6];
};

constexpr WTab make_wtab() {
  WTab W{};
  int p0[21] = {}, p1[21] = {};
  int idx = 0;
  for (int x = 0; x < 7; ++x)
    for (int y = x + 1; y < 7; ++y) { p0[idx] = x; p1[idx] = y; ++idx; }
  int t0[35] = {}, t1[35] = {}, t2[35] = {};
  idx = 0;
  for (int x = 0; x < 7; ++x)
    for (int y = x + 1; y < 7; ++y)
      for (int z = y + 1; z < 7; ++z) { t0[idx] = x; t1[idx] = y; t2[idx] = z; ++idx; }
  int cnt[35] = {};
  for (int a = 0; a < 21; ++a)
    for (int b = 0; b < 21; ++b) {
      int pa0 = p0[a], pa1 = p1[a], pb0 = p0[b], pb1 = p1[b];
      if (pa0 == pb0 || pa0 == pb1 || pa1 == pb0 || pa1 == pb1) continue;
      bool used[7] = {};
      used[pa0] = true; used[pa1] = true; used[pb0] = true; used[pb1] = true;
      int tr[3] = {}; int k = 0;
      for (int x = 0; x < 7; ++x) if (!used[x]) tr[k++] = x;
      int c = -1;
      for (int cc = 0; cc < 35; ++cc)
        if (t0[cc] == tr[0] && t1[cc] == tr[1] && t2[cc] == tr[2]) { c = cc; break; }
      int perm[7] = {pa0, pa1, pb0, pb1, tr[0], tr[1], tr[2]};
      int inv = 0;
      for (int i = 0; i < 7; ++i)
        for (int j = i + 1; j < 7; ++j)
          if (perm[i] > perm[j]) ++inv;
      W.a[c][cnt[c]] = a; W.b[c][cnt[c]] = b; W.sg[c][cnt[c]] = (inv & 1) ? -1 : 1;
      ++cnt[c];
    }
  return W;
}

__device__ __forceinline__ int trioff(int i) { return 21 * i - (i * (i - 1)) / 2; }

// ---------------- kernel A: vol[n] = sqrt(|det(metric_n)|), + sum ----------------
__global__ __launch_bounds__(256) void vol_kernel(const float* __restrict__ metric,
                                                  float* __restrict__ out) {
  const int n = blockIdx.x * 256 + threadIdx.x;
  double a[7][7];
#pragma unroll
  for (int r = 0; r < 7; ++r)
#pragma unroll
    for (int c = 0; c < 7; ++c) a[r][c] = (double)metric[n * 49 + r * 7 + c];

  double det = 1.0;
#pragma unroll
  for (int k = 0; k < 7; ++k) {
#pragma unroll
    for (int r = k + 1; r < 7; ++r) {   // bubble max |pivot| into row k
      bool sw = fabs(a[r][k]) > fabs(a[k][k]);
#pragma unroll
      for (int c = k; c < 7; ++c) {
        double u = a[k][c], v = a[r][c];
        a[k][c] = sw ? v : u;
        a[r][c] = sw ? u : v;
      }
    }
    det *= a[k][k];
    double inv = (a[k][k] != 0.0) ? 1.0 / a[k][k] : 0.0;
#pragma unroll
    for (int r = k + 1; r < 7; ++r) {
      double f = a[r][k] * inv;
#pragma unroll
      for (int c = k + 1; c < 7; ++c) a[r][c] -= f * a[k][c];
    }
  }
  float vol = (float)sqrt(fabs(det));
  out[VOLOFF + n] = vol;

  float s = vol;
#pragma unroll
  for (int off = 32; off > 0; off >>= 1) s += __shfl_down(s, off, 64);
  __shared__ float partial[4];
  const int lane = threadIdx.x & 63, wv = threadIdx.x >> 6;
  if (lane == 0) partial[wv] = s;
  __syncthreads();
  if (threadIdx.x == 0)
    atomicAdd(out + VSUM, partial[0] + partial[1] + partial[2] + partial[3]);
}

// ---------------- kernel B: symmetric tiled contract ----------------
// grid (7 k-tiles, 256 n-chunks) x 256 threads. Thread t<231 owns the t-th
// upper-triangular pair (i<=j). Per n: stage omega + vol*Phi k-tile in LDS;
// D[c] once per pair (210 FMAs); acc[kk] += dot(D, pw_row). Flush atomically
// to the canonical UPPER element only (finalize mirrors to the lower half).
__global__ __launch_bounds__(256) void contract_kernel(const float* __restrict__ omega,
                                                       const float* __restrict__ Phi,
                                                       float* __restrict__ out) {
  constexpr WTab W = make_wtab();
  __shared__ __align__(16) float lds_om[NH2 * 24];  // rows padded to 24 floats
  __shared__ __align__(16) float lds_pw[KT * 36];   // rows padded to 36 floats

  const int t = threadIdx.x;
  const int k0 = blockIdx.x * KT;
  const int n0 = blockIdx.y * CHUNK;
  const bool act = (t < NPAIR);

  // triangular decode: pair t -> (pi <= pj)
  int pi = 0, pj = 0;
  {
    const int p = act ? t : 0;
    int i = 0;
    while (i < 20 && trioff(i + 1) <= p) ++i;
    pi = i;
    pj = p - trioff(i) + i;
  }

  if (t < KT) lds_pw[t * 36 + 35] = 0.0f;  // zero pad col, never overwritten

  float acc[KT];
#pragma unroll
  for (int kk = 0; kk < KT; ++kk) acc[kk] = 0.0f;

  for (int n = n0; n < n0 + CHUNK; ++n) {
    const float vn = out[VOLOFF + n];
    const float* om = omega + n * 441;
    const float* ph = Phi + n * 2695 + k0 * 35;

    __syncthreads();  // previous iteration's consumers done
    {
      int f = t;
      lds_om[(f / 21) * 24 + (f % 21)] = om[f];
      f = t + 256;
      if (f < 441) lds_om[(f / 21) * 24 + (f % 21)] = om[f];
      lds_pw[(t / 35) * 36 + (t % 35)] = vn * ph[t];
      f = t + 256;
      if (f < 385) lds_pw[(f / 35) * 36 + (f % 35)] = vn * ph[f];
    }
    __syncthreads();

    if (act) {
      float wi[21], wj[21];
      const float* oi = lds_om + pi * 24;
      const float* oj = lds_om + pj * 24;
#pragma unroll
      for (int a = 0; a < 20; a += 4) {
        float4 v = *(const float4*)(oi + a);
        wi[a] = v.x; wi[a + 1] = v.y; wi[a + 2] = v.z; wi[a + 3] = v.w;
        float4 u = *(const float4*)(oj + a);
        wj[a] = u.x; wj[a + 1] = u.y; wj[a + 2] = u.z; wj[a + 3] = u.w;
      }
      wi[20] = oi[20]; wj[20] = oj[20];

      float d[36];
#pragma unroll
      for (int c = 0; c < 35; ++c) {
        float dd = 0.0f;
#pragma unroll
        for (int u = 0; u < 6; ++u)
          dd = fmaf((W.sg[c][u] > 0) ? wi[W.a[c][u]] : -wi[W.a[c][u]], wj[W.b[c][u]], dd);
        d[c] = dd;
      }
      d[35] = 0.0f;

#pragma unroll
      for (int kk = 0; kk < KT; ++kk) {
        const float* pw = lds_pw + kk * 36;  // wave-uniform -> LDS broadcast
        float s0 = 0.f, s1 = 0.f, s2 = 0.f, s3 = 0.f;
#pragma unroll
        for (int c = 0; c < 36; c += 4) {
          float4 p = *(const float4*)(pw + c);
          s0 = fmaf(d[c + 0], p.x, s0);
          s1 = fmaf(d[c + 1], p.y, s1);
          s2 = fmaf(d[c + 2], p.z, s2);
          s3 = fmaf(d[c + 3], p.w, s3);
        }
        acc[kk] += (s0 + s1) + (s2 + s3);
      }
    }
  }

  if (act) {
    const int base = (pi * 21 + pj) * 77 + k0;   // canonical upper element only
#pragma unroll
    for (int kk = 0; kk < KT; ++kk) atomicAdd(&out[base + kk], acc[kk]);
  }
}

// ---------------- kernel C1: finalize Y from upper-triangular Sraw -------------
// Thread owns (pair p, k): v = Sraw_upper / volsum; writes +v to (i,j), -v to
// (j,i). Race-free: upper elements read only by their owner; lower only written.
__global__ __launch_bounds__(256) void finalize_y(float* __restrict__ out) {
  const int e = blockIdx.x * 256 + threadIdx.x;
  if (e >= NPAIR * NK) return;
  const int p = e / NK, k = e % NK;
  int i = 0;
  while (i < 20 && trioff(i + 1) <= p) ++i;
  const int j = p - trioff(i) + i;
  const float inv = 1.0f / out[VSUM];
  const float v = out[(i * 21 + j) * NK + k] * inv;
  out[(i * 21 + j) * NK + k] = v;
  if (j != i) out[(j * 21 + i) * NK + k] = -v;
}

// ---------------- kernel C2: M[k,l] = sum_ij Y_ij,k Y_ij,l ----------------
__global__ __launch_bounds__(256) void gram_kernel(const float* __restrict__ Y,
                                                   float* __restrict__ Mout) {
  const int e = blockIdx.x * 256 + threadIdx.x;
  if (e >= M_SIZE) return;
  const int k = e / NK, l = e % NK;
  float acc = 0.0f;
  for (int ij = 0; ij < NIJ; ++ij)
    acc = fmaf(Y[ij * NK + k], Y[ij * NK + l], acc);
  Mout[e] = acc;
}

// ---------------- kernel D: eigvalsh(M), single-wave fp32 ----------------
__global__ __launch_bounds__(64) void eig_kernel(const float* __restrict__ Min,
                                                 float* __restrict__ eout) {
  __shared__ float A[77][79];
  __shared__ float vsh[77], wsh[77], esh[77], dsh[77], e2[76];
  __shared__ float glo_s, ghi_s;
  const int t = threadIdx.x;

  for (int f = t; f < M_SIZE; f += 64) A[f / 77][f % 77] = Min[f];
  __syncthreads();

  // Householder tridiagonalization (fp32, rank-2 update)
  for (int k = 0; k < 75; ++k) {
    const int lo = k + 1;

    float part = 0.0f;
    for (int i = lo + t; i <= 76; i += 64) part += A[i][k] * A[i][k];
#pragma unroll
    for (int off = 32; off > 0; off >>= 1) part += __shfl_down(part, off, 64);
    const float sigma2 = __shfl(part, 0, 64);
    const float x1 = A[lo][k];

    if (sigma2 < 1e-30f) {
      if (t == 0) esh[k] = 0.0f;
      __syncthreads();
      continue;
    }
    const float sigma = sqrtf(sigma2);
    const float alpha = (x1 >= 0.0f) ? -sigma : sigma;
    const float beta = 1.0f / (sigma2 - alpha * x1);  // = 2 / (v^T v)

    for (int i = lo + t; i <= 76; i += 64) vsh[i] = (i == lo) ? (x1 - alpha) : A[i][k];
    if (t == 0) esh[k] = alpha;
    __syncthreads();

    // p = beta * A v  (store into wsh), K = p.v
    float part2 = 0.0f;
    for (int i = lo + t; i <= 76; i += 64) {
      float s = 0.0f;
      for (int j = lo; j <= 76; ++j) s += A[i][j] * vsh[j];
      const float p = beta * s;
      wsh[i] = p;
      part2 += p * vsh[i];
    }
#pragma unroll
    for (int off = 32; off > 0; off >>= 1) part2 += __shfl_down(part2, off, 64);
    const float K = __shfl(part2, 0, 64);
    __syncthreads();

    const float hb = 0.5f * beta * K;
    for (int i = lo + t; i <= 76; i += 64) wsh[i] = wsh[i] - hb * vsh[i];
    __syncthreads();

    // A -= v w^T + w v^T  (row-parallel)
    for (int ii = lo + t; ii <= 76; ii += 64) {
      const float vi = vsh[ii], wi = wsh[ii];
      for (int jj = lo; jj <= 76; ++jj)
        A[ii][jj] -= vi * wsh[jj] + wi * vsh[jj];
    }
    __syncthreads();
  }

  for (int f = t; f < 77; f += 64) dsh[f] = A[f][f];
  if (t == 0) esh[75] = A[76][75];
  __syncthreads();
  for (int f = t; f < 76; f += 64) e2[f] = esh[f] * esh[f];

  if (t == 0) {  // Gershgorin bounds
    float lo_ = 1e30f, hi_ = -1e30f;
    for (int i = 0; i < 77; ++i) {
      float r = ((i > 0) ? fabsf(esh[i - 1]) : 0.0f) + ((i < 76) ? fabsf(esh[i]) : 0.0f);
      lo_ = fminf(lo_, dsh[i] - r);
      hi_ = fmaxf(hi_, dsh[i] + r);
    }
    const float span = hi_ - lo_;
    glo_s = lo_ - 0.001f * span - 1e-6f;
    ghi_s = hi_ + 0.001f * span + 1e-6f;
  }
  __syncthreads();

  // bisection via Sturm count; lane handles eigenvalues idx and idx+64
  for (int idx = t; idx < 77; idx += 64) {
    float lo = glo_s, hi = ghi_s;
    for (int it = 0; it < 48; ++it) {
      const float mid = 0.5f * (lo + hi);
      float q = dsh[0] - mid;
      int cnt = (q < 0.0f);
      for (int i = 1; i < 77; ++i) {
        if (fabsf(q) < 1e-30f) q = -1e-30f;
        q = dsh[i] - mid - e2[i - 1] / q;
        cnt += (q < 0.0f);
      }
      if (cnt > idx) hi = mid; else lo = mid;
    }
    eout[76 - idx] = 0.5f * (lo + hi);  // descending
  }
}

// ---------------- launch ----------------
extern "C" void kernel_launch(void* const* d_in, const int* in_sizes, int n_in,
                              void* d_out, int out_size, void* d_ws, size_t ws_size,
                              hipStream_t stream) {
  // Inputs selected BY ELEMENT COUNT (all distinct), fallback to dict order.
  const float* omega  = (const float*)d_in[0];
  const float* Phi    = (const float*)d_in[1];
  const float* metric = (const float*)d_in[2];
  for (int q = 0; q < n_in && q < 3; ++q) {
    if (in_sizes[q] == SZ_OMEGA)       omega  = (const float*)d_in[q];
    else if (in_sizes[q] == SZ_PHI)    Phi    = (const float*)d_in[q];
    else if (in_sizes[q] == SZ_METRIC) metric = (const float*)d_in[q];
  }

  float* out = (float*)d_out;

  // All scratch lives inside d_out (d_ws unused):
  //   out[0 .. Y_SIZE)            : Sraw accumulator -> finalized Y
  //   out[VOLOFF .. VOLOFF+4096)  : vol[n] (temp, overwritten by gram's M)
  //   out[VSUM]                   : volsum (temp, overwritten by gram's M)
  hipMemsetAsync(d_out, 0, (size_t)out_size * sizeof(float), stream);

  hipLaunchKernelGGL(vol_kernel, dim3(NBATCH / 256), dim3(256), 0, stream, metric, out);
  hipLaunchKernelGGL(contract_kernel, dim3(7, NCHUNK), dim3(256), 0, stream,
                     omega, Phi, out);
  hipLaunchKernelGGL(finalize_y, dim3((NPAIR * NK + 255) / 256), dim3(256), 0, stream,
                     out);
  hipLaunchKernelGGL(gram_kernel, dim3((M_SIZE + 255) / 256), dim3(256), 0, stream,
                     out, out + Y_SIZE);
  hipLaunchKernelGGL(eig_kernel, dim3(1), dim3(64), 0, stream,
                     out + Y_SIZE, out + Y_SIZE + M_SIZE);
}

// Round 7
// 1063.926 us; speedup vs baseline: 3.2532x; 1.3249x over previous
//
#include <hip/hip_runtime.h>
#include <math.h>

#define NBATCH 4096
#define NH2 21
#define NK 77
#define NC 35
#define NIJ 441
#define Y_SIZE 33957
#define M_SIZE 5929
#define VOLOFF Y_SIZE          // vol[n] at out[VOLOFF + n] (temp, inside M region)
#define VSUM (Y_SIZE + 4096)   // volsum at out[VSUM] (temp, inside M region)
#define KT 11                  // k-tile: 7 tiles cover 77
#define CHUNK 16               // n per block
#define NCHUNK (NBATCH / CHUNK)
#define NPAIR 231              // upper-triangular (i<=j) pairs of 21

#define SZ_OMEGA  (NBATCH * NH2 * NH2)   // 1,806,336
#define SZ_PHI    (NBATCH * NK * NC)     // 11,038,720
#define SZ_METRIC (NBATCH * 7 * 7)       // 200,704

// ---------------- compile-time wedge structure constants ----------------
// C[a,b,c] nonzero iff pair_a, pair_b, triple_c partition {0..6}; value = perm
// sign. Exactly 6 (a,b) terms per c. MUST be a constexpr LOCAL in each kernel
// (round-3 finding: __device__ constexpr global risked zero-init).
// C[a,b,c]=C[b,a,c] => S symmetric in (i,j): contract computes only i<=j.
// ROUND-5 LESSON: never cap VGPRs below the ~90-float live set (spill -> 5x).
// ROUND-6 LESSON: single-wave eig with runtime-bound LDS loops = 800 us
// (120-cyc ds_read latency, nothing to hide it); fix = fixed-bound unrolled
// loops + 256 threads.
struct WTab {
  int a[NC][6];
  int b[NC][6];
  int sg[NC][6];
};

constexpr WTab make_wtab() {
  WTab W{};
  int p0[21] = {}, p1[21] = {};
  int idx = 0;
  for (int x = 0; x < 7; ++x)
    for (int y = x + 1; y < 7; ++y) { p0[idx] = x; p1[idx] = y; ++idx; }
  int t0[35] = {}, t1[35] = {}, t2[35] = {};
  idx = 0;
  for (int x = 0; x < 7; ++x)
    for (int y = x + 1; y < 7; ++y)
      for (int z = y + 1; z < 7; ++z) { t0[idx] = x; t1[idx] = y; t2[idx] = z; ++idx; }
  int cnt[35] = {};
  for (int a = 0; a < 21; ++a)
    for (int b = 0; b < 21; ++b) {
      int pa0 = p0[a], pa1 = p1[a], pb0 = p0[b], pb1 = p1[b];
      if (pa0 == pb0 || pa0 == pb1 || pa1 == pb0 || pa1 == pb1) continue;
      bool used[7] = {};
      used[pa0] = true; used[pa1] = true; used[pb0] = true; used[pb1] = true;
      int tr[3] = {}; int k = 0;
      for (int x = 0; x < 7; ++x) if (!used[x]) tr[k++] = x;
      int c = -1;
      for (int cc = 0; cc < 35; ++cc)
        if (t0[cc] == tr[0] && t1[cc] == tr[1] && t2[cc] == tr[2]) { c = cc; break; }
      int perm[7] = {pa0, pa1, pb0, pb1, tr[0], tr[1], tr[2]};
      int inv = 0;
      for (int i = 0; i < 7; ++i)
        for (int j = i + 1; j < 7; ++j)
          if (perm[i] > perm[j]) ++inv;
      W.a[c][cnt[c]] = a; W.b[c][cnt[c]] = b; W.sg[c][cnt[c]] = (inv & 1) ? -1 : 1;
      ++cnt[c];
    }
  return W;
}

__device__ __forceinline__ int trioff(int i) { return 21 * i - (i * (i - 1)) / 2; }

// ---------------- kernel A: vol[n] = sqrt(|det(metric_n)|), + sum ----------------
__global__ __launch_bounds__(256) void vol_kernel(const float* __restrict__ metric,
                                                  float* __restrict__ out) {
  const int n = blockIdx.x * 256 + threadIdx.x;
  double a[7][7];
#pragma unroll
  for (int r = 0; r < 7; ++r)
#pragma unroll
    for (int c = 0; c < 7; ++c) a[r][c] = (double)metric[n * 49 + r * 7 + c];

  double det = 1.0;
#pragma unroll
  for (int k = 0; k < 7; ++k) {
#pragma unroll
    for (int r = k + 1; r < 7; ++r) {   // bubble max |pivot| into row k
      bool sw = fabs(a[r][k]) > fabs(a[k][k]);
#pragma unroll
      for (int c = k; c < 7; ++c) {
        double u = a[k][c], v = a[r][c];
        a[k][c] = sw ? v : u;
        a[r][c] = sw ? u : v;
      }
    }
    det *= a[k][k];
    double inv = (a[k][k] != 0.0) ? 1.0 / a[k][k] : 0.0;
#pragma unroll
    for (int r = k + 1; r < 7; ++r) {
      double f = a[r][k] * inv;
#pragma unroll
      for (int c = k + 1; c < 7; ++c) a[r][c] -= f * a[k][c];
    }
  }
  float vol = (float)sqrt(fabs(det));
  out[VOLOFF + n] = vol;

  float s = vol;
#pragma unroll
  for (int off = 32; off > 0; off >>= 1) s += __shfl_down(s, off, 64);
  __shared__ float partial[4];
  const int lane = threadIdx.x & 63, wv = threadIdx.x >> 6;
  if (lane == 0) partial[wv] = s;
  __syncthreads();
  if (threadIdx.x == 0)
    atomicAdd(out + VSUM, partial[0] + partial[1] + partial[2] + partial[3]);
}

// ---------------- kernel B: symmetric tiled contract (unchanged from R6) --------
__global__ __launch_bounds__(256) void contract_kernel(const float* __restrict__ omega,
                                                       const float* __restrict__ Phi,
                                                       float* __restrict__ out) {
  constexpr WTab W = make_wtab();
  __shared__ __align__(16) float lds_om[NH2 * 24];  // rows padded to 24 floats
  __shared__ __align__(16) float lds_pw[KT * 36];   // rows padded to 36 floats

  const int t = threadIdx.x;
  const int k0 = blockIdx.x * KT;
  const int n0 = blockIdx.y * CHUNK;
  const bool act = (t < NPAIR);

  // triangular decode: pair t -> (pi <= pj)
  int pi = 0, pj = 0;
  {
    const int p = act ? t : 0;
    int i = 0;
    while (i < 20 && trioff(i + 1) <= p) ++i;
    pi = i;
    pj = p - trioff(i) + i;
  }

  if (t < KT) lds_pw[t * 36 + 35] = 0.0f;  // zero pad col, never overwritten

  float acc[KT];
#pragma unroll
  for (int kk = 0; kk < KT; ++kk) acc[kk] = 0.0f;

  for (int n = n0; n < n0 + CHUNK; ++n) {
    const float vn = out[VOLOFF + n];
    const float* om = omega + n * 441;
    const float* ph = Phi + n * 2695 + k0 * 35;

    __syncthreads();  // previous iteration's consumers done
    {
      int f = t;
      lds_om[(f / 21) * 24 + (f % 21)] = om[f];
      f = t + 256;
      if (f < 441) lds_om[(f / 21) * 24 + (f % 21)] = om[f];
      lds_pw[(t / 35) * 36 + (t % 35)] = vn * ph[t];
      f = t + 256;
      if (f < 385) lds_pw[(f / 35) * 36 + (f % 35)] = vn * ph[f];
    }
    __syncthreads();

    if (act) {
      float wi[21], wj[21];
      const float* oi = lds_om + pi * 24;
      const float* oj = lds_om + pj * 24;
#pragma unroll
      for (int a = 0; a < 20; a += 4) {
        float4 v = *(const float4*)(oi + a);
        wi[a] = v.x; wi[a + 1] = v.y; wi[a + 2] = v.z; wi[a + 3] = v.w;
        float4 u = *(const float4*)(oj + a);
        wj[a] = u.x; wj[a + 1] = u.y; wj[a + 2] = u.z; wj[a + 3] = u.w;
      }
      wi[20] = oi[20]; wj[20] = oj[20];

      float d[36];
#pragma unroll
      for (int c = 0; c < 35; ++c) {
        float dd = 0.0f;
#pragma unroll
        for (int u = 0; u < 6; ++u)
          dd = fmaf((W.sg[c][u] > 0) ? wi[W.a[c][u]] : -wi[W.a[c][u]], wj[W.b[c][u]], dd);
        d[c] = dd;
      }
      d[35] = 0.0f;

#pragma unroll
      for (int kk = 0; kk < KT; ++kk) {
        const float* pw = lds_pw + kk * 36;  // wave-uniform -> LDS broadcast
        float s0 = 0.f, s1 = 0.f, s2 = 0.f, s3 = 0.f;
#pragma unroll
        for (int c = 0; c < 36; c += 4) {
          float4 p = *(const float4*)(pw + c);
          s0 = fmaf(d[c + 0], p.x, s0);
          s1 = fmaf(d[c + 1], p.y, s1);
          s2 = fmaf(d[c + 2], p.z, s2);
          s3 = fmaf(d[c + 3], p.w, s3);
        }
        acc[kk] += (s0 + s1) + (s2 + s3);
      }
    }
  }

  if (act) {
    const int base = (pi * 21 + pj) * 77 + k0;   // canonical upper element only
#pragma unroll
    for (int kk = 0; kk < KT; ++kk) atomicAdd(&out[base + kk], acc[kk]);
  }
}

// ---------------- kernel C1: finalize Y from upper-triangular Sraw -------------
__global__ __launch_bounds__(256) void finalize_y(float* __restrict__ out) {
  const int e = blockIdx.x * 256 + threadIdx.x;
  if (e >= NPAIR * NK) return;
  const int p = e / NK, k = e % NK;
  int i = 0;
  while (i < 20 && trioff(i + 1) <= p) ++i;
  const int j = p - trioff(i) + i;
  const float inv = 1.0f / out[VSUM];
  const float v = out[(i * 21 + j) * NK + k] * inv;
  out[(i * 21 + j) * NK + k] = v;
  if (j != i) out[(j * 21 + i) * NK + k] = -v;
}

// ---------------- kernel C2: M[k,l] = sum_ij Y_ij,k Y_ij,l ----------------
__global__ __launch_bounds__(256) void gram_kernel(const float* __restrict__ Y,
                                                   float* __restrict__ Mout) {
  const int e = blockIdx.x * 256 + threadIdx.x;
  if (e >= M_SIZE) return;
  const int k = e / NK, l = e % NK;
  float acc = 0.0f;
  for (int ij = 0; ij < NIJ; ++ij)
    acc = fmaf(Y[ij * NK + k], Y[ij * NK + l], acc);
  Mout[e] = acc;
}

// ---------------- kernel D: eigvalsh(M) — 256 threads, fp32, fixed bounds ------
// All inner loops are compile-time 0..77 (fully unrolled -> LDS loads batched
// at throughput, not 120-cyc serialized latency). Correctness with full-range
// rank-2 updates: BOTH v and w are masked to the active window (k+1..76), so
// out-of-window updates are exact no-ops; frozen rows never change.
// A kept symmetric -> sigma2/x1 read from ROW k (conflict-free lane reads).
__global__ __launch_bounds__(256) void eig_kernel(const float* __restrict__ Min,
                                                  float* __restrict__ eout) {
  __shared__ float A[77][79];   // stride 79: 15t mod 32 -> conflict-free columns
  __shared__ float vsh[80], wsh[80], esh[77], dsh[77], e2[76];
  __shared__ float red[4];
  __shared__ float glo_s, ghi_s;
  const int t = threadIdx.x;
  const int lane = t & 63, wv = t >> 6;

  for (int f = t; f < M_SIZE; f += 256) A[f / 77][f % 77] = Min[f];
  __syncthreads();

  for (int k = 0; k < 75; ++k) {
    // sigma2 = sum_{i>k} A[k][i]^2  (row k == column k, A symmetric)
    const float x = (t < 77) ? A[k][t] : 0.0f;
    const bool act = (t > k) && (t < 77);
    float part = act ? x * x : 0.0f;
#pragma unroll
    for (int off = 32; off > 0; off >>= 1) part += __shfl_down(part, off, 64);
    if (lane == 0) red[wv] = part;
    __syncthreads();
    const float sigma2 = red[0] + red[1] + red[2] + red[3];
    const float x1 = A[k][k + 1];   // wave-uniform -> broadcast read

    if (sigma2 < 1e-26f) {          // uniform branch
      if (t == 0) esh[k] = 0.0f;
      __syncthreads();
      continue;
    }
    const float sigma = sqrtf(sigma2);
    const float alpha = (x1 >= 0.0f) ? -sigma : sigma;
    const float beta = 1.0f / (sigma2 - alpha * x1);  // = 2 / (v^T v)

    // v masked to window; zero elsewhere (incl. pad 77..79)
    const float vt = act ? ((t == k + 1) ? (x1 - alpha) : x) : 0.0f;
    if (t < 80) vsh[t] = vt;
    if (t == 0) esh[k] = alpha;
    __syncthreads();

    // p_t = beta * (A v)_t over the FULL row (v zero-padded -> exact)
    float p = 0.0f;
    if (t < 77) {
      const float* Ar = &A[t][0];
      float s0 = 0.f, s1 = 0.f, s2 = 0.f, s3 = 0.f;
#pragma unroll
      for (int j = 0; j < 76; j += 4) {
        s0 = fmaf(Ar[j + 0], vsh[j + 0], s0);
        s1 = fmaf(Ar[j + 1], vsh[j + 1], s1);
        s2 = fmaf(Ar[j + 2], vsh[j + 2], s2);
        s3 = fmaf(Ar[j + 3], vsh[j + 3], s3);
      }
      p = ((s0 + s1) + (s2 + s3)) + Ar[76] * vsh[76];
      p *= beta;
    }
    float part2 = (t < 77) ? p * vt : 0.0f;   // vt masked -> garbage p harmless
#pragma unroll
    for (int off = 32; off > 0; off >>= 1) part2 += __shfl_down(part2, off, 64);
    __syncthreads();                // red[] free for reuse
    if (lane == 0) red[wv] = part2;
    __syncthreads();
    const float K = red[0] + red[1] + red[2] + red[3];
    const float hb = 0.5f * beta * K;

    const float wt = act ? (p - hb * vt) : 0.0f;   // w masked too (critical!)
    if (t < 80) wsh[t] = wt;
    __syncthreads();

    // A -= v w^T + w v^T, full range (no-op outside window since v,w masked)
    if (t < 77) {
      float* Ar = &A[t][0];
#pragma unroll
      for (int j = 0; j < 77; ++j)
        Ar[j] -= vt * wsh[j] + wt * vsh[j];
    }
    __syncthreads();
  }

  if (t < 77) dsh[t] = A[t][t];
  if (t == 0) esh[75] = A[76][75];
  __syncthreads();
  if (t < 76) e2[t] = esh[t] * esh[t];

  if (t == 0) {  // Gershgorin bounds
    float lo_ = 1e30f, hi_ = -1e30f;
    for (int i = 0; i < 77; ++i) {
      float r = ((i > 0) ? fabsf(esh[i - 1]) : 0.0f) + ((i < 76) ? fabsf(esh[i]) : 0.0f);
      lo_ = fminf(lo_, dsh[i] - r);
      hi_ = fmaxf(hi_, dsh[i] + r);
    }
    const float span = hi_ - lo_;
    glo_s = lo_ - 0.001f * span - 1e-6f;
    ghi_s = hi_ + 0.001f * span + 1e-6f;
  }
  __syncthreads();

  // bisection via Sturm count — one eigenvalue per thread, single pass
  if (t < 77) {
    float lo = glo_s, hi = ghi_s;
    for (int it = 0; it < 38; ++it) {
      const float mid = 0.5f * (lo + hi);
      float q = dsh[0] - mid;
      int cnt = (q < 0.0f);
#pragma unroll 4
      for (int i = 1; i < 77; ++i) {
        if (fabsf(q) < 1e-30f) q = -1e-30f;
        q = dsh[i] - mid - e2[i - 1] / q;
        cnt += (q < 0.0f);
      }
      if (cnt > t) hi = mid; else lo = mid;
    }
    eout[76 - t] = 0.5f * (lo + hi);  // descending
  }
}

// ---------------- launch ----------------
extern "C" void kernel_launch(void* const* d_in, const int* in_sizes, int n_in,
                              void* d_out, int out_size, void* d_ws, size_t ws_size,
                              hipStream_t stream) {
  // Inputs selected BY ELEMENT COUNT (all distinct), fallback to dict order.
  const float* omega  = (const float*)d_in[0];
  const float* Phi    = (const float*)d_in[1];
  const float* metric = (const float*)d_in[2];
  for (int q = 0; q < n_in && q < 3; ++q) {
    if (in_sizes[q] == SZ_OMEGA)       omega  = (const float*)d_in[q];
    else if (in_sizes[q] == SZ_PHI)    Phi    = (const float*)d_in[q];
    else if (in_sizes[q] == SZ_METRIC) metric = (const float*)d_in[q];
  }

  float* out = (float*)d_out;

  // All scratch lives inside d_out (d_ws unused):
  //   out[0 .. Y_SIZE)            : Sraw accumulator -> finalized Y
  //   out[VOLOFF .. VOLOFF+4096)  : vol[n] (temp, overwritten by gram's M)
  //   out[VSUM]                   : volsum (temp, overwritten by gram's M)
  hipMemsetAsync(d_out, 0, (size_t)out_size * sizeof(float), stream);

  hipLaunchKernelGGL(vol_kernel, dim3(NBATCH / 256), dim3(256), 0, stream, metric, out);
  hipLaunchKernelGGL(contract_kernel, dim3(7, NCHUNK), dim3(256), 0, stream,
                     omega, Phi, out);
  hipLaunchKernelGGL(finalize_y, dim3((NPAIR * NK + 255) / 256), dim3(256), 0, stream,
                     out);
  hipLaunchKernelGGL(gram_kernel, dim3((M_SIZE + 255) / 256), dim3(256), 0, stream,
                     out, out + Y_SIZE);
  hipLaunchKernelGGL(eig_kernel, dim3(1), dim3(256), 0, stream,
                     out + Y_SIZE, out + Y_SIZE + M_SIZE);
}

// Round 8
// 1005.686 us; speedup vs baseline: 3.4416x; 1.0579x over previous
//
#include <hip/hip_runtime.h>
#include <math.h>

#define NBATCH 4096
#define NH2 21
#define NK 77
#define NC 35
#define NIJ 441
#define Y_SIZE 33957
#define M_SIZE 5929
#define VOLOFF Y_SIZE          // vol[n] at out[VOLOFF + n] (temp, inside M region)
#define VSUM (Y_SIZE + 4096)   // volsum at out[VSUM] (temp, inside M region)
#define KT 11                  // k-tile: 7 tiles cover 77
#define CHUNK 16               // n per block
#define NCHUNK (NBATCH / CHUNK)
#define NPAIR 231              // upper-triangular (i<=j) pairs of 21

#define SZ_OMEGA  (NBATCH * NH2 * NH2)   // 1,806,336
#define SZ_PHI    (NBATCH * NK * NC)     // 11,038,720
#define SZ_METRIC (NBATCH * 7 * 7)       // 200,704

// ---------------- compile-time wedge structure constants ----------------
// C[a,b,c] nonzero iff pair_a, pair_b, triple_c partition {0..6}; value = perm
// sign. Exactly 6 (a,b) terms per c. MUST be a constexpr LOCAL in each kernel
// (round-3 finding: __device__ constexpr global risked zero-init).
// C[a,b,c]=C[b,a,c] => S symmetric in (i,j): contract computes only i<=j.
// ROUND-5 LESSON: never cap VGPRs below the ~90-float live set (spill -> 5x).
// ROUND-6 LESSON: runtime-bound LDS loops in a 1-wave kernel = 120-cyc
// serialized ds_read latency; use fixed bounds + enough threads.
// ROUND-7 LESSON: omega row stride 24 (6 bank-groups, gcd(6,8)=2) caused
// 1.38e7 conflict cycles; stride 28 (7 groups, coprime 8) is conflict-free
// for b128 reads. Staging without prefetch leaves load latency naked between
// the two barriers -> VALUBusy 26%.
struct WTab {
  int a[NC][6];
  int b[NC][6];
  int sg[NC][6];
};

constexpr WTab make_wtab() {
  WTab W{};
  int p0[21] = {}, p1[21] = {};
  int idx = 0;
  for (int x = 0; x < 7; ++x)
    for (int y = x + 1; y < 7; ++y) { p0[idx] = x; p1[idx] = y; ++idx; }
  int t0[35] = {}, t1[35] = {}, t2[35] = {};
  idx = 0;
  for (int x = 0; x < 7; ++x)
    for (int y = x + 1; y < 7; ++y)
      for (int z = y + 1; z < 7; ++z) { t0[idx] = x; t1[idx] = y; t2[idx] = z; ++idx; }
  int cnt[35] = {};
  for (int a = 0; a < 21; ++a)
    for (int b = 0; b < 21; ++b) {
      int pa0 = p0[a], pa1 = p1[a], pb0 = p0[b], pb1 = p1[b];
      if (pa0 == pb0 || pa0 == pb1 || pa1 == pb0 || pa1 == pb1) continue;
      bool used[7] = {};
      used[pa0] = true; used[pa1] = true; used[pb0] = true; used[pb1] = true;
      int tr[3] = {}; int k = 0;
      for (int x = 0; x < 7; ++x) if (!used[x]) tr[k++] = x;
      int c = -1;
      for (int cc = 0; cc < 35; ++cc)
        if (t0[cc] == tr[0] && t1[cc] == tr[1] && t2[cc] == tr[2]) { c = cc; break; }
      int perm[7] = {pa0, pa1, pb0, pb1, tr[0], tr[1], tr[2]};
      int inv = 0;
      for (int i = 0; i < 7; ++i)
        for (int j = i + 1; j < 7; ++j)
          if (perm[i] > perm[j]) ++inv;
      W.a[c][cnt[c]] = a; W.b[c][cnt[c]] = b; W.sg[c][cnt[c]] = (inv & 1) ? -1 : 1;
      ++cnt[c];
    }
  return W;
}

__device__ __forceinline__ int trioff(int i) { return 21 * i - (i * (i - 1)) / 2; }

// ---------------- kernel A: vol[n] = sqrt(|det(metric_n)|), + sum ----------------
__global__ __launch_bounds__(256) void vol_kernel(const float* __restrict__ metric,
                                                  float* __restrict__ out) {
  const int n = blockIdx.x * 256 + threadIdx.x;
  double a[7][7];
#pragma unroll
  for (int r = 0; r < 7; ++r)
#pragma unroll
    for (int c = 0; c < 7; ++c) a[r][c] = (double)metric[n * 49 + r * 7 + c];

  double det = 1.0;
#pragma unroll
  for (int k = 0; k < 7; ++k) {
#pragma unroll
    for (int r = k + 1; r < 7; ++r) {   // bubble max |pivot| into row k
      bool sw = fabs(a[r][k]) > fabs(a[k][k]);
#pragma unroll
      for (int c = k; c < 7; ++c) {
        double u = a[k][c], v = a[r][c];
        a[k][c] = sw ? v : u;
        a[r][c] = sw ? u : v;
      }
    }
    det *= a[k][k];
    double inv = (a[k][k] != 0.0) ? 1.0 / a[k][k] : 0.0;
#pragma unroll
    for (int r = k + 1; r < 7; ++r) {
      double f = a[r][k] * inv;
#pragma unroll
      for (int c = k + 1; c < 7; ++c) a[r][c] -= f * a[k][c];
    }
  }
  float vol = (float)sqrt(fabs(det));
  out[VOLOFF + n] = vol;

  float s = vol;
#pragma unroll
  for (int off = 32; off > 0; off >>= 1) s += __shfl_down(s, off, 64);
  __shared__ float partial[4];
  const int lane = threadIdx.x & 63, wv = threadIdx.x >> 6;
  if (lane == 0) partial[wv] = s;
  __syncthreads();
  if (threadIdx.x == 0)
    atomicAdd(out + VSUM, partial[0] + partial[1] + partial[2] + partial[3]);
}

// ---------------- kernel B: symmetric tiled contract, software-pipelined --------
// grid (7 k-tiles, 256 n-chunks) x 256 threads. Thread t<231 owns the t-th
// upper-triangular pair (i<=j). Pipeline: while computing n, the next n's
// omega/Phi/vol are in flight into registers (coalesced scalar loads); LDS
// write + 2 barriers per iter. omega rows padded to 28 floats (conflict-free
// b128); Phi staged RAW, vn folded into the final accumulate.
__global__ __launch_bounds__(256) void contract_kernel(const float* __restrict__ omega,
                                                       const float* __restrict__ Phi,
                                                       float* __restrict__ out) {
  constexpr WTab W = make_wtab();
  __shared__ __align__(16) float lds_om[NH2 * 28];  // stride 28 -> b128 conflict-free
  __shared__ __align__(16) float lds_pw[KT * 36];   // raw Phi tile rows (+zero pad col)

  const int t = threadIdx.x;
  const int k0 = blockIdx.x * KT;
  const int n0 = blockIdx.y * CHUNK;
  const bool act = (t < NPAIR);

  // triangular decode: pair t -> (pi <= pj)
  int pi = 0, pj = 0;
  {
    const int p = act ? t : 0;
    int i = 0;
    while (i < 20 && trioff(i + 1) <= p) ++i;
    pi = i;
    pj = p - trioff(i) + i;
  }

  // staging roles + LDS scatter offsets (uniform over the n loop)
  const int f1 = t + 256;
  const bool hasA1 = (f1 < 441);
  const bool hasB1 = (f1 < 385);
  const int oA0 = (t / 21) * 28 + (t % 21);
  const int oA1 = (f1 / 21) * 28 + (f1 % 21);
  const int oB0 = (t / 35) * 36 + (t % 35);
  const int oB1 = (f1 / 35) * 36 + (f1 % 35);

  if (t < KT) lds_pw[t * 36 + 35] = 0.0f;  // zero pad col (never overwritten)

  float acc[KT];
#pragma unroll
  for (int kk = 0; kk < KT; ++kk) acc[kk] = 0.0f;

  // prologue: load n0 into registers
  {
    const float* om = omega + n0 * 441;
    const float* ph = Phi + n0 * 2695 + k0 * 35;
    // (loads issued below via the named registers)
  }
  const float* om_p = omega + n0 * 441;
  const float* ph_p = Phi + n0 * 2695 + k0 * 35;
  float rA0 = om_p[t];
  float rA1 = hasA1 ? om_p[f1] : 0.0f;
  float rB0 = ph_p[t];                   // t < 256 < 385 always valid
  float rB1 = hasB1 ? ph_p[f1] : 0.0f;
  float rvn = out[VOLOFF + n0];

  for (int n = n0; n < n0 + CHUNK; ++n) {
    __syncthreads();                     // previous iter's LDS consumers done
    lds_om[oA0] = rA0;
    if (hasA1) lds_om[oA1] = rA1;
    lds_pw[oB0] = rB0;
    if (hasB1) lds_pw[oB1] = rB1;
    const float vn = rvn;
    __syncthreads();

    if (n + 1 < n0 + CHUNK) {            // prefetch n+1 during compute
      const float* om2 = omega + (n + 1) * 441;
      const float* ph2 = Phi + (n + 1) * 2695 + k0 * 35;
      rA0 = om2[t];
      if (hasA1) rA1 = om2[f1];
      rB0 = ph2[t];
      if (hasB1) rB1 = ph2[f1];
      rvn = out[VOLOFF + n + 1];
    }

    if (act) {
      float wi[21], wj[21];
      const float* oi = lds_om + pi * 28;
      const float* oj = lds_om + pj * 28;
#pragma unroll
      for (int a = 0; a < 20; a += 4) {
        float4 v = *(const float4*)(oi + a);
        wi[a] = v.x; wi[a + 1] = v.y; wi[a + 2] = v.z; wi[a + 3] = v.w;
        float4 u = *(const float4*)(oj + a);
        wj[a] = u.x; wj[a + 1] = u.y; wj[a + 2] = u.z; wj[a + 3] = u.w;
      }
      wi[20] = oi[20]; wj[20] = oj[20];

      float d[36];
#pragma unroll
      for (int c = 0; c < 35; ++c) {
        float dd = 0.0f;
#pragma unroll
        for (int u = 0; u < 6; ++u)
          dd = fmaf((W.sg[c][u] > 0) ? wi[W.a[c][u]] : -wi[W.a[c][u]], wj[W.b[c][u]], dd);
        d[c] = dd;
      }
      d[35] = 0.0f;

#pragma unroll
      for (int kk = 0; kk < KT; ++kk) {
        const float* pw = lds_pw + kk * 36;  // wave-uniform -> LDS broadcast
        float s0 = 0.f, s1 = 0.f, s2 = 0.f, s3 = 0.f;
#pragma unroll
        for (int c = 0; c < 36; c += 4) {
          float4 p = *(const float4*)(pw + c);
          s0 = fmaf(d[c + 0], p.x, s0);
          s1 = fmaf(d[c + 1], p.y, s1);
          s2 = fmaf(d[c + 2], p.z, s2);
          s3 = fmaf(d[c + 3], p.w, s3);
        }
        acc[kk] = fmaf(vn, (s0 + s1) + (s2 + s3), acc[kk]);  // vn folded here
      }
    }
  }

  if (act) {
    const int base = (pi * 21 + pj) * 77 + k0;   // canonical upper element only
#pragma unroll
    for (int kk = 0; kk < KT; ++kk) atomicAdd(&out[base + kk], acc[kk]);
  }
}

// ---------------- kernel C1: finalize Y from upper-triangular Sraw -------------
__global__ __launch_bounds__(256) void finalize_y(float* __restrict__ out) {
  const int e = blockIdx.x * 256 + threadIdx.x;
  if (e >= NPAIR * NK) return;
  const int p = e / NK, k = e % NK;
  int i = 0;
  while (i < 20 && trioff(i + 1) <= p) ++i;
  const int j = p - trioff(i) + i;
  const float inv = 1.0f / out[VSUM];
  const float v = out[(i * 21 + j) * NK + k] * inv;
  out[(i * 21 + j) * NK + k] = v;
  if (j != i) out[(j * 21 + i) * NK + k] = -v;
}

// ---------------- kernel C2: M[k,l] = sum_ij Y_ij,k Y_ij,l ----------------
__global__ __launch_bounds__(256) void gram_kernel(const float* __restrict__ Y,
                                                   float* __restrict__ Mout) {
  const int e = blockIdx.x * 256 + threadIdx.x;
  if (e >= M_SIZE) return;
  const int k = e / NK, l = e % NK;
  float acc = 0.0f;
  for (int ij = 0; ij < NIJ; ++ij)
    acc = fmaf(Y[ij * NK + k], Y[ij * NK + l], acc);
  Mout[e] = acc;
}

// ---------------- kernel D: eigvalsh(M) — 256 threads, fp32, fixed bounds ------
__global__ __launch_bounds__(256) void eig_kernel(const float* __restrict__ Min,
                                                  float* __restrict__ eout) {
  __shared__ float A[77][79];   // stride 79 -> conflict-free column access
  __shared__ float vsh[80], wsh[80], esh[77], dsh[77], e2[76];
  __shared__ float red[4];
  __shared__ float glo_s, ghi_s;
  const int t = threadIdx.x;
  const int lane = t & 63, wv = t >> 6;

  for (int f = t; f < M_SIZE; f += 256) A[f / 77][f % 77] = Min[f];
  __syncthreads();

  for (int k = 0; k < 75; ++k) {
    const float x = (t < 77) ? A[k][t] : 0.0f;
    const bool act = (t > k) && (t < 77);
    float part = act ? x * x : 0.0f;
#pragma unroll
    for (int off = 32; off > 0; off >>= 1) part += __shfl_down(part, off, 64);
    if (lane == 0) red[wv] = part;
    __syncthreads();
    const float sigma2 = red[0] + red[1] + red[2] + red[3];
    const float x1 = A[k][k + 1];

    if (sigma2 < 1e-26f) {
      if (t == 0) esh[k] = 0.0f;
      __syncthreads();
      continue;
    }
    const float sigma = sqrtf(sigma2);
    const float alpha = (x1 >= 0.0f) ? -sigma : sigma;
    const float beta = 1.0f / (sigma2 - alpha * x1);  // = 2 / (v^T v)

    const float vt = act ? ((t == k + 1) ? (x1 - alpha) : x) : 0.0f;
    if (t < 80) vsh[t] = vt;
    if (t == 0) esh[k] = alpha;
    __syncthreads();

    float p = 0.0f;
    if (t < 77) {
      const float* Ar = &A[t][0];
      float s0 = 0.f, s1 = 0.f, s2 = 0.f, s3 = 0.f;
#pragma unroll
      for (int j = 0; j < 76; j += 4) {
        s0 = fmaf(Ar[j + 0], vsh[j + 0], s0);
        s1 = fmaf(Ar[j + 1], vsh[j + 1], s1);
        s2 = fmaf(Ar[j + 2], vsh[j + 2], s2);
        s3 = fmaf(Ar[j + 3], vsh[j + 3], s3);
      }
      p = ((s0 + s1) + (s2 + s3)) + Ar[76] * vsh[76];
      p *= beta;
    }
    float part2 = (t < 77) ? p * vt : 0.0f;
#pragma unroll
    for (int off = 32; off > 0; off >>= 1) part2 += __shfl_down(part2, off, 64);
    __syncthreads();
    if (lane == 0) red[wv] = part2;
    __syncthreads();
    const float K = red[0] + red[1] + red[2] + red[3];
    const float hb = 0.5f * beta * K;

    const float wt = act ? (p - hb * vt) : 0.0f;
    if (t < 80) wsh[t] = wt;
    __syncthreads();

    if (t < 77) {
      float* Ar = &A[t][0];
#pragma unroll
      for (int j = 0; j < 77; ++j)
        Ar[j] -= vt * wsh[j] + wt * vsh[j];
    }
    __syncthreads();
  }

  if (t < 77) dsh[t] = A[t][t];
  if (t == 0) esh[75] = A[76][75];
  __syncthreads();
  if (t < 76) e2[t] = esh[t] * esh[t];

  if (t == 0) {  // Gershgorin bounds
    float lo_ = 1e30f, hi_ = -1e30f;
    for (int i = 0; i < 77; ++i) {
      float r = ((i > 0) ? fabsf(esh[i - 1]) : 0.0f) + ((i < 76) ? fabsf(esh[i]) : 0.0f);
      lo_ = fminf(lo_, dsh[i] - r);
      hi_ = fmaxf(hi_, dsh[i] + r);
    }
    const float span = hi_ - lo_;
    glo_s = lo_ - 0.001f * span - 1e-6f;
    ghi_s = hi_ + 0.001f * span + 1e-6f;
  }
  __syncthreads();

  if (t < 77) {  // bisection via Sturm count, one eigenvalue per thread
    float lo = glo_s, hi = ghi_s;
    for (int it = 0; it < 38; ++it) {
      const float mid = 0.5f * (lo + hi);
      float q = dsh[0] - mid;
      int cnt = (q < 0.0f);
#pragma unroll 4
      for (int i = 1; i < 77; ++i) {
        if (fabsf(q) < 1e-30f) q = -1e-30f;
        q = dsh[i] - mid - e2[i - 1] / q;
        cnt += (q < 0.0f);
      }
      if (cnt > t) hi = mid; else lo = mid;
    }
    eout[76 - t] = 0.5f * (lo + hi);  // descending
  }
}

// ---------------- launch ----------------
extern "C" void kernel_launch(void* const* d_in, const int* in_sizes, int n_in,
                              void* d_out, int out_size, void* d_ws, size_t ws_size,
                              hipStream_t stream) {
  // Inputs selected BY ELEMENT COUNT (all distinct), fallback to dict order.
  const float* omega  = (const float*)d_in[0];
  const float* Phi    = (const float*)d_in[1];
  const float* metric = (const float*)d_in[2];
  for (int q = 0; q < n_in && q < 3; ++q) {
    if (in_sizes[q] == SZ_OMEGA)       omega  = (const float*)d_in[q];
    else if (in_sizes[q] == SZ_PHI)    Phi    = (const float*)d_in[q];
    else if (in_sizes[q] == SZ_METRIC) metric = (const float*)d_in[q];
  }

  float* out = (float*)d_out;

  // All scratch lives inside d_out (d_ws unused):
  //   out[0 .. Y_SIZE)            : Sraw accumulator -> finalized Y
  //   out[VOLOFF .. VOLOFF+4096)  : vol[n] (temp, overwritten by gram's M)
  //   out[VSUM]                   : volsum (temp, overwritten by gram's M)
  hipMemsetAsync(d_out, 0, (size_t)out_size * sizeof(float), stream);

  hipLaunchKernelGGL(vol_kernel, dim3(NBATCH / 256), dim3(256), 0, stream, metric, out);
  hipLaunchKernelGGL(contract_kernel, dim3(7, NCHUNK), dim3(256), 0, stream,
                     omega, Phi, out);
  hipLaunchKernelGGL(finalize_y, dim3((NPAIR * NK + 255) / 256), dim3(256), 0, stream,
                     out);
  hipLaunchKernelGGL(gram_kernel, dim3((M_SIZE + 255) / 256), dim3(256), 0, stream,
                     out, out + Y_SIZE);
  hipLaunchKernelGGL(eig_kernel, dim3(1), dim3(256), 0, stream,
                     out + Y_SIZE, out + Y_SIZE + M_SIZE);
}

// Round 9
// 642.631 us; speedup vs baseline: 5.3860x; 1.5650x over previous
//
#include <hip/hip_runtime.h>
#include <math.h>

#define NBATCH 4096
#define NH2 21
#define NK 77
#define NC 35
#define NIJ 441
#define Y_SIZE 33957
#define M_SIZE 5929
#define VOLOFF Y_SIZE          // vol[n] at out[VOLOFF + n] (temp, inside M region)
#define VSUM (Y_SIZE + 4096)   // volsum at out[VSUM] (temp, inside M region)
#define NPAIR 231              // upper-triangular (i<=j) pairs of 21
#define BLK 512                // contract block threads (8 waves)
#define NPB 8                  // n per contract block
#define GRID_B (NBATCH / NPB)  // 512 blocks

#define SZ_OMEGA  (NBATCH * NH2 * NH2)   // 1,806,336
#define SZ_PHI    (NBATCH * NK * NC)     // 11,038,720
#define SZ_METRIC (NBATCH * 7 * 7)       // 200,704

// ---------------- compile-time wedge structure constants ----------------
// C[a,b,c] nonzero iff pair_a, pair_b, triple_c partition {0..6}; value = perm
// sign. Exactly 6 (a,b) terms per c. MUST be a constexpr LOCAL in each kernel
// (round-3 finding). C[a,b,c]=C[b,a,c] => S symmetric in (i,j): only i<=j pairs.
// R5: never cap VGPRs below live set (spill -> 5x).
// R6: runtime-bound LDS loops in 1-wave kernel = serialized 120-cyc ds_reads.
// R7: LDS row strides whose bank-group count shares a factor with 8 -> conflicts.
// R8: the 2-barrier staged VALU loop plateaus at ~27% VALUBusy (compiler drains
// vmcnt(0) at every s_barrier; ~75% stall). Fix = move the k-contraction to
// MFMA (this round): S[p,q] = sum_{n,c} D[p,nc] * PW[nc,q] as bf16 GEMM.
struct WTab {
  int a[NC][6];
  int b[NC][6];
  int sg[NC][6];
};

constexpr WTab make_wtab() {
  WTab W{};
  int p0[21] = {}, p1[21] = {};
  int idx = 0;
  for (int x = 0; x < 7; ++x)
    for (int y = x + 1; y < 7; ++y) { p0[idx] = x; p1[idx] = y; ++idx; }
  int t0[35] = {}, t1[35] = {}, t2[35] = {};
  idx = 0;
  for (int x = 0; x < 7; ++x)
    for (int y = x + 1; y < 7; ++y)
      for (int z = y + 1; z < 7; ++z) { t0[idx] = x; t1[idx] = y; t2[idx] = z; ++idx; }
  int cnt[35] = {};
  for (int a = 0; a < 21; ++a)
    for (int b = 0; b < 21; ++b) {
      int pa0 = p0[a], pa1 = p1[a], pb0 = p0[b], pb1 = p1[b];
      if (pa0 == pb0 || pa0 == pb1 || pa1 == pb0 || pa1 == pb1) continue;
      bool used[7] = {};
      used[pa0] = true; used[pa1] = true; used[pb0] = true; used[pb1] = true;
      int tr[3] = {}; int k = 0;
      for (int x = 0; x < 7; ++x) if (!used[x]) tr[k++] = x;
      int c = -1;
      for (int cc = 0; cc < 35; ++cc)
        if (t0[cc] == tr[0] && t1[cc] == tr[1] && t2[cc] == tr[2]) { c = cc; break; }
      int perm[7] = {pa0, pa1, pb0, pb1, tr[0], tr[1], tr[2]};
      int inv = 0;
      for (int i = 0; i < 7; ++i)
        for (int j = i + 1; j < 7; ++j)
          if (perm[i] > perm[j]) ++inv;
      W.a[c][cnt[c]] = a; W.b[c][cnt[c]] = b; W.sg[c][cnt[c]] = (inv & 1) ? -1 : 1;
      ++cnt[c];
    }
  return W;
}

__device__ __forceinline__ int trioff(int i) { return 21 * i - (i * (i - 1)) / 2; }

// fp32 -> bf16 (RNE), returns low 16 bits
__device__ __forceinline__ unsigned f2bf(float x) {
  union { float f; unsigned u; } v; v.f = x;
  return ((v.u + 0x7FFFu + ((v.u >> 16) & 1u)) >> 16) & 0xFFFFu;
}

typedef float f32x4 __attribute__((ext_vector_type(4)));
typedef short s16x8 __attribute__((ext_vector_type(8)));

// ---------------- kernel A: vol[n] = sqrt(|det(metric_n)|), + sum ----------------
__global__ __launch_bounds__(256) void vol_kernel(const float* __restrict__ metric,
                                                  float* __restrict__ out) {
  const int n = blockIdx.x * 256 + threadIdx.x;
  double a[7][7];
#pragma unroll
  for (int r = 0; r < 7; ++r)
#pragma unroll
    for (int c = 0; c < 7; ++c) a[r][c] = (double)metric[n * 49 + r * 7 + c];

  double det = 1.0;
#pragma unroll
  for (int k = 0; k < 7; ++k) {
#pragma unroll
    for (int r = k + 1; r < 7; ++r) {   // bubble max |pivot| into row k
      bool sw = fabs(a[r][k]) > fabs(a[k][k]);
#pragma unroll
      for (int c = k; c < 7; ++c) {
        double u = a[k][c], v = a[r][c];
        a[k][c] = sw ? v : u;
        a[r][c] = sw ? u : v;
      }
    }
    det *= a[k][k];
    double inv = (a[k][k] != 0.0) ? 1.0 / a[k][k] : 0.0;
#pragma unroll
    for (int r = k + 1; r < 7; ++r) {
      double f = a[r][k] * inv;
#pragma unroll
      for (int c = k + 1; c < 7; ++c) a[r][c] -= f * a[k][c];
    }
  }
  float vol = (float)sqrt(fabs(det));
  out[VOLOFF + n] = vol;

  float s = vol;
#pragma unroll
  for (int off = 32; off > 0; off >>= 1) s += __shfl_down(s, off, 64);
  __shared__ float partial[4];
  const int lane = threadIdx.x & 63, wv = threadIdx.x >> 6;
  if (lane == 0) partial[wv] = s;
  __syncthreads();
  if (threadIdx.x == 0)
    atomicAdd(out + VSUM, partial[0] + partial[1] + partial[2] + partial[3]);
}

// ---------------- kernel B: MFMA contract ----------------
// GEMM view: S[p,q] = sum_{n,c} D[p, n*64+c] * PW[n*64+c, q], bf16 inputs,
// fp32 accumulate. Per block (512 thr, 8 waves): NPB n's; per n:
//   stage omega(fp32, stride 28) + PW^T(bf16, [q][c] rows, stride 80, vn folded)
//   compute D[231][35] bf16 once (halves split c-ranges across thread halves)
//   2 K-steps of mfma_f32_16x16x32_bf16: 16 M-tiles x 5 N-tiles, 2 Mt/wave.
// Layout sources (HW-verified): A[m=lane&15][k=quad*8+j]; B rows = [q][k];
// C/D col=lane&15, row=quad*4+reg. Pads zeroed pre-loop (NaN hygiene); unused
// M rows 231..255 / N cols 77..79 only affect unflushed outputs.
__global__ __launch_bounds__(BLK) void contract_kernel(const float* __restrict__ omega,
                                                       const float* __restrict__ Phi,
                                                       float* __restrict__ out) {
  constexpr WTab W = make_wtab();
  __shared__ __align__(16) short ldsD[256 * 80];  // D rows, stride 80 bf16
  __shared__ __align__(16) short ldsP[80 * 80];   // PW^T rows [q][k], stride 80
  __shared__ __align__(16) float ldsO[NH2 * 28];  // omega rows, stride 28 fp32

  const int t = threadIdx.x;
  const int lane = t & 63;
  const int wv = t >> 6;        // 0..7
  const int quad = lane >> 4;   // 0..3
  const int col = lane & 15;    // m for A-frags, q for B-frags, col for C
  const int n0 = blockIdx.x * NPB;

  // zero D and P fully (k-pads 35..63 MUST be 0; rest harmless)
  for (int f = t; f < 256 * 40; f += BLK) ((int*)ldsD)[f] = 0;
  for (int f = t; f < 80 * 40; f += BLK) ((int*)ldsP)[f] = 0;

  // D-compute role: threads 0..230 do pair t, c in [0,18);
  //                 threads 256..486 do pair t-256, c in [18,35).
  const bool roleA = (t < NPAIR);
  const bool roleB = (t >= 256) && (t < 256 + NPAIR);
  int pi = 0, pj = 0;
  {
    const int p = roleA ? t : (roleB ? (t - 256) : 0);
    int i = 0;
    while (i < 20 && trioff(i + 1) <= p) ++i;
    pi = i;
    pj = p - trioff(i) + i;
  }

  // prologue: prefetch n0 into registers
  float rA = 0.0f, rB[6], rvn;
  {
    const float* om = omega + n0 * 441;
    const float* ph = Phi + n0 * 2695;
    if (t < 441) rA = om[t];
#pragma unroll
    for (int j = 0; j < 6; ++j) {
      const int e = t + j * BLK;
      rB[j] = (e < 2695) ? ph[e] : 0.0f;
    }
    rvn = out[VOLOFF + n0];
  }

  f32x4 acc[2][5];
#pragma unroll
  for (int mi = 0; mi < 2; ++mi)
#pragma unroll
    for (int nt = 0; nt < 5; ++nt) acc[mi][nt] = (f32x4){0.f, 0.f, 0.f, 0.f};

  for (int it = 0; it < NPB; ++it) {
    __syncthreads();  // zeros done (it=0) / prior MFMA reads done

    // stage omega + PW^T (vn folded) from prefetched registers
    if (t < 441) ldsO[(t / 21) * 28 + (t % 21)] = rA;
    {
      const float vn = rvn;
#pragma unroll
      for (int j = 0; j < 6; ++j) {
        const int e = t + j * BLK;
        if (e < 2695) {
          const int q = e / 35, c = e % 35;
          ldsP[q * 80 + c] = (short)f2bf(vn * rB[j]);
        }
      }
    }
    __syncthreads();  // stage visible

    // prefetch n+1 (drains at next barrier -> covered by D-phase)
    if (it + 1 < NPB) {
      const int n1 = n0 + it + 1;
      const float* om2 = omega + n1 * 441;
      const float* ph2 = Phi + n1 * 2695;
      if (t < 441) rA = om2[t];
#pragma unroll
      for (int j = 0; j < 6; ++j) {
        const int e = t + j * BLK;
        if (e < 2695) rB[j] = ph2[e];
      }
      rvn = out[VOLOFF + n1];
    }

    // D-compute (bf16 rows of ldsD)
    if (roleA || roleB) {
      float wi[21], wj[21];
      const float* oi = ldsO + pi * 28;
      const float* oj = ldsO + pj * 28;
#pragma unroll
      for (int a = 0; a < 20; a += 4) {
        float4 v = *(const float4*)(oi + a);
        wi[a] = v.x; wi[a + 1] = v.y; wi[a + 2] = v.z; wi[a + 3] = v.w;
        float4 u = *(const float4*)(oj + a);
        wj[a] = u.x; wj[a + 1] = u.y; wj[a + 2] = u.z; wj[a + 3] = u.w;
      }
      wi[20] = oi[20]; wj[20] = oj[20];

      if (roleA) {
        float d[18];
#pragma unroll
        for (int c = 0; c < 18; ++c) {
          float dd = 0.0f;
#pragma unroll
          for (int u = 0; u < 6; ++u)
            dd = fmaf((W.sg[c][u] > 0) ? wi[W.a[c][u]] : -wi[W.a[c][u]], wj[W.b[c][u]], dd);
          d[c] = dd;
        }
        int* Drow = (int*)ldsD + t * 40;
#pragma unroll
        for (int k2 = 0; k2 < 9; ++k2)
          Drow[k2] = (int)(f2bf(d[2 * k2]) | (f2bf(d[2 * k2 + 1]) << 16));
      } else {
        float d[17];
#pragma unroll
        for (int c = 18; c < 35; ++c) {
          float dd = 0.0f;
#pragma unroll
          for (int u = 0; u < 6; ++u)
            dd = fmaf((W.sg[c][u] > 0) ? wi[W.a[c][u]] : -wi[W.a[c][u]], wj[W.b[c][u]], dd);
          d[c - 18] = dd;
        }
        int* Drow = (int*)ldsD + (t - 256) * 40;
#pragma unroll
        for (int k2 = 0; k2 < 8; ++k2)
          Drow[9 + k2] = (int)(f2bf(d[2 * k2]) | (f2bf(d[2 * k2 + 1]) << 16));
        Drow[17] = (int)f2bf(d[16]);   // (c=34, pad c=35 = 0)
      }
    }
    __syncthreads();  // D visible

    // MFMA: 2 K-steps x (2 M-tiles/wave x 5 N-tiles)
#pragma unroll
    for (int s = 0; s < 2; ++s) {
      const int kof = s * 32 + quad * 8;
      s16x8 a0 = *(const s16x8*)(ldsD + ((wv * 2 + 0) * 16 + col) * 80 + kof);
      s16x8 a1 = *(const s16x8*)(ldsD + ((wv * 2 + 1) * 16 + col) * 80 + kof);
      s16x8 b[5];
#pragma unroll
      for (int nt = 0; nt < 5; ++nt)
        b[nt] = *(const s16x8*)(ldsP + (nt * 16 + col) * 80 + kof);
#pragma unroll
      for (int nt = 0; nt < 5; ++nt) {
        acc[0][nt] = __builtin_amdgcn_mfma_f32_16x16x32_bf16(a0, b[nt], acc[0][nt], 0, 0, 0);
        acc[1][nt] = __builtin_amdgcn_mfma_f32_16x16x32_bf16(a1, b[nt], acc[1][nt], 0, 0, 0);
      }
    }
  }

  // flush: C row m = mt*16 + quad*4 + r (pair index), col q = nt*16 + col
#pragma unroll
  for (int mi = 0; mi < 2; ++mi) {
    const int mt = wv * 2 + mi;
#pragma unroll
    for (int r = 0; r < 4; ++r) {
      const int m = mt * 16 + quad * 4 + r;
      if (m < NPAIR) {
        int i = 0;
        while (i < 20 && trioff(i + 1) <= m) ++i;
        const int jj = m - trioff(i) + i;
        const int base = (i * 21 + jj) * 77;
#pragma unroll
        for (int nt = 0; nt < 5; ++nt) {
          const int q = nt * 16 + col;
          if (q < 77) atomicAdd(&out[base + q], acc[mi][nt][r]);
        }
      }
    }
  }
}

// ---------------- kernel C1: finalize Y from upper-triangular Sraw -------------
__global__ __launch_bounds__(256) void finalize_y(float* __restrict__ out) {
  const int e = blockIdx.x * 256 + threadIdx.x;
  if (e >= NPAIR * NK) return;
  const int p = e / NK, k = e % NK;
  int i = 0;
  while (i < 20 && trioff(i + 1) <= p) ++i;
  const int j = p - trioff(i) + i;
  const float inv = 1.0f / out[VSUM];
  const float v = out[(i * 21 + j) * NK + k] * inv;
  out[(i * 21 + j) * NK + k] = v;
  if (j != i) out[(j * 21 + i) * NK + k] = -v;
}

// ---------------- kernel C2: M[k,l] = sum_ij Y_ij,k Y_ij,l ----------------
__global__ __launch_bounds__(256) void gram_kernel(const float* __restrict__ Y,
                                                   float* __restrict__ Mout) {
  const int e = blockIdx.x * 256 + threadIdx.x;
  if (e >= M_SIZE) return;
  const int k = e / NK, l = e % NK;
  float acc = 0.0f;
  for (int ij = 0; ij < NIJ; ++ij)
    acc = fmaf(Y[ij * NK + k], Y[ij * NK + l], acc);
  Mout[e] = acc;
}

// ---------------- kernel D: eigvalsh(M) — 256 threads, fp32, fixed bounds ------
__global__ __launch_bounds__(256) void eig_kernel(const float* __restrict__ Min,
                                                  float* __restrict__ eout) {
  __shared__ float A[77][79];
  __shared__ float vsh[80], wsh[80], esh[77], dsh[77], e2[76];
  __shared__ float red[4];
  __shared__ float glo_s, ghi_s;
  const int t = threadIdx.x;
  const int lane = t & 63, wv = t >> 6;

  for (int f = t; f < M_SIZE; f += 256) A[f / 77][f % 77] = Min[f];
  __syncthreads();

  for (int k = 0; k < 75; ++k) {
    const float x = (t < 77) ? A[k][t] : 0.0f;
    const bool act = (t > k) && (t < 77);
    float part = act ? x * x : 0.0f;
#pragma unroll
    for (int off = 32; off > 0; off >>= 1) part += __shfl_down(part, off, 64);
    if (lane == 0) red[wv] = part;
    __syncthreads();
    const float sigma2 = red[0] + red[1] + red[2] + red[3];
    const float x1 = A[k][k + 1];

    if (sigma2 < 1e-26f) {
      if (t == 0) esh[k] = 0.0f;
      __syncthreads();
      continue;
    }
    const float sigma = sqrtf(sigma2);
    const float alpha = (x1 >= 0.0f) ? -sigma : sigma;
    const float beta = 1.0f / (sigma2 - alpha * x1);

    const float vt = act ? ((t == k + 1) ? (x1 - alpha) : x) : 0.0f;
    if (t < 80) vsh[t] = vt;
    if (t == 0) esh[k] = alpha;
    __syncthreads();

    float p = 0.0f;
    if (t < 77) {
      const float* Ar = &A[t][0];
      float s0 = 0.f, s1 = 0.f, s2 = 0.f, s3 = 0.f;
#pragma unroll
      for (int j = 0; j < 76; j += 4) {
        s0 = fmaf(Ar[j + 0], vsh[j + 0], s0);
        s1 = fmaf(Ar[j + 1], vsh[j + 1], s1);
        s2 = fmaf(Ar[j + 2], vsh[j + 2], s2);
        s3 = fmaf(Ar[j + 3], vsh[j + 3], s3);
      }
      p = ((s0 + s1) + (s2 + s3)) + Ar[76] * vsh[76];
      p *= beta;
    }
    float part2 = (t < 77) ? p * vt : 0.0f;
#pragma unroll
    for (int off = 32; off > 0; off >>= 1) part2 += __shfl_down(part2, off, 64);
    __syncthreads();
    if (lane == 0) red[wv] = part2;
    __syncthreads();
    const float K = red[0] + red[1] + red[2] + red[3];
    const float hb = 0.5f * beta * K;

    const float wt = act ? (p - hb * vt) : 0.0f;
    if (t < 80) wsh[t] = wt;
    __syncthreads();

    if (t < 77) {
      float* Ar = &A[t][0];
#pragma unroll
      for (int j = 0; j < 77; ++j)
        Ar[j] -= vt * wsh[j] + wt * vsh[j];
    }
    __syncthreads();
  }

  if (t < 77) dsh[t] = A[t][t];
  if (t == 0) esh[75] = A[76][75];
  __syncthreads();
  if (t < 76) e2[t] = esh[t] * esh[t];

  if (t == 0) {
    float lo_ = 1e30f, hi_ = -1e30f;
    for (int i = 0; i < 77; ++i) {
      float r = ((i > 0) ? fabsf(esh[i - 1]) : 0.0f) + ((i < 76) ? fabsf(esh[i]) : 0.0f);
      lo_ = fminf(lo_, dsh[i] - r);
      hi_ = fmaxf(hi_, dsh[i] + r);
    }
    const float span = hi_ - lo_;
    glo_s = lo_ - 0.001f * span - 1e-6f;
    ghi_s = hi_ + 0.001f * span + 1e-6f;
  }
  __syncthreads();

  if (t < 77) {
    float lo = glo_s, hi = ghi_s;
    for (int it = 0; it < 38; ++it) {
      const float mid = 0.5f * (lo + hi);
      float q = dsh[0] - mid;
      int cnt = (q < 0.0f);
#pragma unroll 4
      for (int i = 1; i < 77; ++i) {
        if (fabsf(q) < 1e-30f) q = -1e-30f;
        q = dsh[i] - mid - e2[i - 1] / q;
        cnt += (q < 0.0f);
      }
      if (cnt > t) hi = mid; else lo = mid;
    }
    eout[76 - t] = 0.5f * (lo + hi);
  }
}

// ---------------- launch ----------------
extern "C" void kernel_launch(void* const* d_in, const int* in_sizes, int n_in,
                              void* d_out, int out_size, void* d_ws, size_t ws_size,
                              hipStream_t stream) {
  const float* omega  = (const float*)d_in[0];
  const float* Phi    = (const float*)d_in[1];
  const float* metric = (const float*)d_in[2];
  for (int q = 0; q < n_in && q < 3; ++q) {
    if (in_sizes[q] == SZ_OMEGA)       omega  = (const float*)d_in[q];
    else if (in_sizes[q] == SZ_PHI)    Phi    = (const float*)d_in[q];
    else if (in_sizes[q] == SZ_METRIC) metric = (const float*)d_in[q];
  }

  float* out = (float*)d_out;

  // All scratch inside d_out (d_ws unused):
  //   out[0 .. Y_SIZE)            : Sraw accumulator -> finalized Y
  //   out[VOLOFF .. VOLOFF+4096)  : vol[n] (temp, overwritten by gram's M)
  //   out[VSUM]                   : volsum (temp, overwritten by gram's M)
  hipMemsetAsync(d_out, 0, (size_t)out_size * sizeof(float), stream);

  hipLaunchKernelGGL(vol_kernel, dim3(NBATCH / 256), dim3(256), 0, stream, metric, out);
  hipLaunchKernelGGL(contract_kernel, dim3(GRID_B), dim3(BLK), 0, stream,
                     omega, Phi, out);
  hipLaunchKernelGGL(finalize_y, dim3((NPAIR * NK + 255) / 256), dim3(256), 0, stream,
                     out);
  hipLaunchKernelGGL(gram_kernel, dim3((M_SIZE + 255) / 256), dim3(256), 0, stream,
                     out, out + Y_SIZE);
  hipLaunchKernelGGL(eig_kernel, dim3(1), dim3(256), 0, stream,
                     out + Y_SIZE, out + Y_SIZE + M_SIZE);
}